// Round 13
// baseline (156.987 us; speedup 1.0000x reference)
//
#include <hip/hip_runtime.h>
#include <stdint.h>

#define B_TOT 16384
#define IN_DIM 128
#define H1 256
#define H2 128
#define NC 10

// LDS byte layout (snn): W2T [256][128] f32 | WoT [128][10] f32 | 16x1KB scr
#define W2T_BYTES (H1 * H2 * 4)            // 131072
#define WOT_OFF   W2T_BYTES
#define WOT_BYTES (H2 * NC * 4)            // 5120
#define SCR_OFF   (WOT_OFF + WOT_BYTES)    // 136192
#define LDS_BYTES (SCR_OFF + 16 * 1024)    // 152576

typedef float v2f __attribute__((ext_vector_type(2)));

// ---------------------------------------------------------------------------
// Kernel A (fused): blocks 0..255 = register-blocked GEMM (64 rows/block,
// thread = 4 neurons x 16 rows, x-tile broadcast from LDS, W1 from L2);
// block 256 = W2/Wo transpose. Per-(row,n) FMA chain is k-ascending in
// 4-chunks, identical to the verified r2 gemm -> bit-exact cur1.
// ---------------------------------------------------------------------------
__global__ __launch_bounds__(256) void gemm1_fused_kernel(
    const float* __restrict__ x, const float* __restrict__ W1,
    const float* __restrict__ b1, const float* __restrict__ W2,
    const float* __restrict__ Wo, float* __restrict__ cur1,
    float* __restrict__ W2T, float* __restrict__ WoT) {
  const int tid = threadIdx.x;
  if (blockIdx.x == 256) {  // transpose block
    for (int idx = tid; idx < H2 * H1; idx += 256) {
      const int o = idx >> 8;
      const int j = idx & 255;
      W2T[j * H2 + o] = W2[idx];
    }
    for (int idx = tid; idx < NC * H2; idx += 256) {
      const int o = idx >> 7;
      const int j = idx & 127;
      WoT[j * NC + o] = Wo[idx];
    }
    return;
  }

  __shared__ float xs[64 * 128];  // 32 KB
  const long row0 = (long)blockIdx.x * 64;
  const float4* xt = (const float4*)(x + row0 * IN_DIM);
  float4* xs4 = (float4*)xs;
#pragma unroll
  for (int i = 0; i < 8; ++i) xs4[tid + i * 256] = xt[tid + i * 256];
  __syncthreads();

  const int n0 = 4 * (tid & 63);
  const int rb = 16 * (tid >> 6);

  float4 acc[16];
#pragma unroll
  for (int r = 0; r < 16; ++r) acc[r] = make_float4(0.f, 0.f, 0.f, 0.f);

  const float* w0p = W1 + (n0 + 0) * IN_DIM;
  const float* w1p = W1 + (n0 + 1) * IN_DIM;
  const float* w2p = W1 + (n0 + 2) * IN_DIM;
  const float* w3p = W1 + (n0 + 3) * IN_DIM;

  for (int k0 = 0; k0 < IN_DIM; k0 += 4) {
    const float4 w0 = *(const float4*)(w0p + k0);
    const float4 w1 = *(const float4*)(w1p + k0);
    const float4 w2 = *(const float4*)(w2p + k0);
    const float4 w3 = *(const float4*)(w3p + k0);
#pragma unroll
    for (int r = 0; r < 16; ++r) {
      const float4 xv = *(const float4*)(xs + (rb + r) * IN_DIM + k0);
      acc[r].x = fmaf(w0.x, xv.x, acc[r].x);
      acc[r].x = fmaf(w0.y, xv.y, acc[r].x);
      acc[r].x = fmaf(w0.z, xv.z, acc[r].x);
      acc[r].x = fmaf(w0.w, xv.w, acc[r].x);
      acc[r].y = fmaf(w1.x, xv.x, acc[r].y);
      acc[r].y = fmaf(w1.y, xv.y, acc[r].y);
      acc[r].y = fmaf(w1.z, xv.z, acc[r].y);
      acc[r].y = fmaf(w1.w, xv.w, acc[r].y);
      acc[r].z = fmaf(w2.x, xv.x, acc[r].z);
      acc[r].z = fmaf(w2.y, xv.y, acc[r].z);
      acc[r].z = fmaf(w2.z, xv.z, acc[r].z);
      acc[r].z = fmaf(w2.w, xv.w, acc[r].z);
      acc[r].w = fmaf(w3.x, xv.x, acc[r].w);
      acc[r].w = fmaf(w3.y, xv.y, acc[r].w);
      acc[r].w = fmaf(w3.z, xv.z, acc[r].w);
      acc[r].w = fmaf(w3.w, xv.w, acc[r].w);
    }
  }
  const float4 bias = *(const float4*)(b1 + n0);
#pragma unroll
  for (int r = 0; r < 16; ++r) {
    float4 o;
    o.x = acc[r].x + bias.x;
    o.y = acc[r].y + bias.y;
    o.z = acc[r].z + bias.z;
    o.w = acc[r].w + bias.w;
    *(float4*)(cur1 + (row0 + rb + r) * H1 + n0) = o;
  }
}

__device__ __forceinline__ int mbcnt64(unsigned long long m) {
  return (int)__builtin_amdgcn_mbcnt_hi(
      (unsigned)(m >> 32), __builtin_amdgcn_mbcnt_lo((unsigned)m, 0u));
}

// Bit-exact serial fallbacks (never expected to trigger; keep exactness
// when a per-row list would overflow 64 entries). Masks recomputed from
// live membrane registers, so group masks need not stay alive.
__device__ __noinline__ v2f serial_main(float n0, float n1, float n2, float n3,
                                        const char* w2b) {
  unsigned long long m0 = __ballot(n0 > 1.0f);
  unsigned long long m1 = __ballot(n1 > 1.0f);
  unsigned long long m2 = __ballot(n2 > 1.0f);
  unsigned long long m3 = __ballot(n3 > 1.0f);
  v2f acc = {0.f, 0.f};
  while (m0) { const int j = (int)__builtin_ctzll(m0); m0 &= m0 - 1;
    acc += *(const v2f*)(w2b + (j << 9)); }
  while (m1) { const int j = (int)__builtin_ctzll(m1); m1 &= m1 - 1;
    acc += *(const v2f*)(w2b + ((64 + j) << 9)); }
  while (m2) { const int j = (int)__builtin_ctzll(m2); m2 &= m2 - 1;
    acc += *(const v2f*)(w2b + ((128 + j) << 9)); }
  while (m3) { const int j = (int)__builtin_ctzll(m3); m3 &= m3 - 1;
    acc += *(const v2f*)(w2b + ((192 + j) << 9)); }
  return acc;
}

__device__ __noinline__ float serial_out(float m2a, float m2b,
                                         const char* wob) {
  unsigned long long me = __ballot(m2a > 1.0f);
  unsigned long long mo = __ballot(m2b > 1.0f);
  float co = 0.f;
  while (me) { const int j = (int)__builtin_ctzll(me); me &= me - 1;
    co += *(const float*)(wob + j * 80); }
  while (mo) { const int j = (int)__builtin_ctzll(mo); mo &= mo - 1;
    co += *(const float*)(wob + j * 80 + 40); }
  return co;
}

// ---------------------------------------------------------------------------
// Kernel B: fused 20-step recurrent SNN. 256 persistent blocks (1/CU),
// 16 waves/block, 4 rows/wave ALL interleaved in one t-loop (r12's pair
// interleave widened to 4 independent streams). Rank-compacted int
// byte-offset lists (4 x 64 per wave), 8-wide ds_read_b64 clusters with
// quad->pair->single drains + exact 4/2/1 tails, no padding. Per-row
// addend order bit-identical to r2/r7: groups 0..3 ascending, j
// ascending, bias last; output layer evens-then-odds.
// ---------------------------------------------------------------------------
__global__ __launch_bounds__(1024) void snn_kernel(
    const float* __restrict__ cur1, const float* __restrict__ W2Tg,
    const float* __restrict__ WoTg, const float* __restrict__ b2,
    const float* __restrict__ bo, const int* __restrict__ nsp,
    float* __restrict__ out) {
  extern __shared__ float lds[];

  const int tid = threadIdx.x;
  {
    float4* dst = (float4*)lds;
    const float4* src = (const float4*)W2Tg;
#pragma unroll
    for (int i = 0; i < 8; ++i) dst[tid + i * 1024] = src[tid + i * 1024];
    if (tid < 320)
      ((float4*)((char*)lds + WOT_OFF))[tid] = ((const float4*)WoTg)[tid];
  }
  __syncthreads();

  const int w = tid >> 6;
  const int l = tid & 63;
  const int lo = (l < NC) ? l : 0;
  const float bb0 = b2[2 * l];
  const float bb1 = b2[2 * l + 1];
  const float bol = bo[lo];
  const int nsteps = *nsp;

  int* scr = (int*)((char*)lds + SCR_OFF) + w * 256;
  int* sA = scr;
  int* sB = scr + 64;
  int* sC = scr + 128;
  int* sD = scr + 192;
  const char* w2b = (const char*)lds + 8 * l;
  const char* wob = (const char*)lds + WOT_OFF + 4 * lo;

  const int wr0 = l << 9;
  const int wr1 = (64 + l) << 9;
  const int wr2 = (128 + l) << 9;
  const int wr3 = (192 + l) << 9;
  const int or0 = 80 * l;
  const int or1 = 80 * l + 40;

#define LOAD8(P, scrp, kk)                                  \
  const int4 P##ia = *(const int4*)((scrp) + (kk));         \
  const int4 P##ib = *(const int4*)((scrp) + (kk) + 4);     \
  const v2f P##p0 = *(const v2f*)(w2b + P##ia.x);           \
  const v2f P##p1 = *(const v2f*)(w2b + P##ia.y);           \
  const v2f P##p2 = *(const v2f*)(w2b + P##ia.z);           \
  const v2f P##p3 = *(const v2f*)(w2b + P##ia.w);           \
  const v2f P##p4 = *(const v2f*)(w2b + P##ib.x);           \
  const v2f P##p5 = *(const v2f*)(w2b + P##ib.y);           \
  const v2f P##p6 = *(const v2f*)(w2b + P##ib.z);           \
  const v2f P##p7 = *(const v2f*)(w2b + P##ib.w);

#define ADD8(P, acc)                                        \
  acc += P##p0; acc += P##p1; acc += P##p2; acc += P##p3;   \
  acc += P##p4; acc += P##p5; acc += P##p6; acc += P##p7;

#define TAILS(scrp, S, acc)                                 \
  {                                                         \
    int k = ((S) >> 3) << 3;                                \
    if ((S) & 4) {                                          \
      const int4 ia = *(const int4*)((scrp) + k);           \
      const v2f p0 = *(const v2f*)(w2b + ia.x);             \
      const v2f p1 = *(const v2f*)(w2b + ia.y);             \
      const v2f p2 = *(const v2f*)(w2b + ia.z);             \
      const v2f p3 = *(const v2f*)(w2b + ia.w);             \
      acc += p0; acc += p1; acc += p2; acc += p3;           \
      k += 4;                                               \
    }                                                       \
    if ((S) & 2) {                                          \
      const int2 ia = *(const int2*)((scrp) + k);           \
      const v2f p0 = *(const v2f*)(w2b + ia.x);             \
      const v2f p1 = *(const v2f*)(w2b + ia.y);             \
      acc += p0; acc += p1;                                 \
      k += 2;                                               \
    }                                                       \
    if ((S) & 1) {                                          \
      const v2f p0 = *(const v2f*)(w2b + (scrp)[k]);        \
      acc += p0;                                            \
    }                                                       \
  }

#define OLOAD8(P, scrp, kk)                                 \
  const int4 P##ia = *(const int4*)((scrp) + (kk));         \
  const int4 P##ib = *(const int4*)((scrp) + (kk) + 4);     \
  const float P##q0 = *(const float*)(wob + P##ia.x);       \
  const float P##q1 = *(const float*)(wob + P##ia.y);       \
  const float P##q2 = *(const float*)(wob + P##ia.z);       \
  const float P##q3 = *(const float*)(wob + P##ia.w);       \
  const float P##q4 = *(const float*)(wob + P##ib.x);       \
  const float P##q5 = *(const float*)(wob + P##ib.y);       \
  const float P##q6 = *(const float*)(wob + P##ib.z);       \
  const float P##q7 = *(const float*)(wob + P##ib.w);

#define OADD8(P, co)                                        \
  co += P##q0; co += P##q1; co += P##q2; co += P##q3;       \
  co += P##q4; co += P##q5; co += P##q6; co += P##q7;

#define OTAILS(scrp, S, co)                                 \
  {                                                         \
    int k = ((S) >> 3) << 3;                                \
    if ((S) & 4) {                                          \
      const int4 ia = *(const int4*)((scrp) + k);           \
      const float u0 = *(const float*)(wob + ia.x);         \
      const float u1 = *(const float*)(wob + ia.y);         \
      const float u2 = *(const float*)(wob + ia.z);         \
      const float u3 = *(const float*)(wob + ia.w);         \
      co += u0; co += u1; co += u2; co += u3;               \
      k += 4;                                               \
    }                                                       \
    if ((S) & 2) {                                          \
      const int2 ia = *(const int2*)((scrp) + k);           \
      const float u0 = *(const float*)(wob + ia.x);         \
      const float u1 = *(const float*)(wob + ia.y);         \
      co += u0; co += u1;                                   \
      k += 2;                                               \
    }                                                       \
    if ((S) & 1) {                                          \
      co += *(const float*)(wob + (scrp)[k]);               \
    }                                                       \
  }

// build one row's main list (masks g0..g3, flags s0..s3, prefixes)
#define BUILD_MAIN(sq, s0, s1, s2, s3, g0, g1, g2, g3, p0, p01, p012)  \
  if (s0) (sq)[mbcnt64(g0)] = wr0;                                     \
  if (s1) { const int rk = (p0) + mbcnt64(g1);                         \
            if (rk < 64) (sq)[rk] = wr1; }                             \
  if (s2) { const int rk = (p01) + mbcnt64(g2);                        \
            if (rk < 64) (sq)[rk] = wr2; }                             \
  if (s3) { const int rk = (p012) + mbcnt64(g3);                       \
            if (rk < 64) (sq)[rk] = wr3; }

  const long b0 = (long)blockIdx.x * 64 + w * 4;

  float c[4][4];
#pragma unroll
  for (int q = 0; q < 4; ++q)
#pragma unroll
    for (int i = 0; i < 4; ++i) c[q][i] = cur1[(b0 + q) * H1 + i * 64 + l];

  float m1v[4][4], sp1[4][4];
#pragma unroll
  for (int q = 0; q < 4; ++q)
#pragma unroll
    for (int i = 0; i < 4; ++i) { m1v[q][i] = 0.f; sp1[q][i] = 0.f; }
  float m2a[4] = {0.f, 0.f, 0.f, 0.f}, m2b[4] = {0.f, 0.f, 0.f, 0.f};
  float sp2a[4] = {0.f, 0.f, 0.f, 0.f}, sp2b[4] = {0.f, 0.f, 0.f, 0.f};
  float mo[4] = {0.f, 0.f, 0.f, 0.f}, spo[4] = {0.f, 0.f, 0.f, 0.f};
  float cnt[4] = {0.f, 0.f, 0.f, 0.f};

  for (int t = 0; t < nsteps; ++t) {
    // ---- layer 1 LIF + spike masks, 4 rows x 4 groups ----
    unsigned long long g[4][4];
    bool s[4][4];
    int S[4], pA[4], pAB[4], pABC[4];
#pragma unroll
    for (int q = 0; q < 4; ++q) {
#pragma unroll
      for (int i = 0; i < 4; ++i) {
        m1v[q][i] = fmaf(0.5f, m1v[q][i], c[q][i]) - sp1[q][i];
        s[q][i] = m1v[q][i] > 1.0f;
        sp1[q][i] = s[q][i] ? 1.0f : 0.0f;
        g[q][i] = __ballot(s[q][i]);
      }
      pA[q] = (int)__popcll(g[q][0]);
      pAB[q] = pA[q] + (int)__popcll(g[q][1]);
      pABC[q] = pAB[q] + (int)__popcll(g[q][2]);
      S[q] = pABC[q] + (int)__popcll(g[q][3]);
    }

    // ---- build 4 lists under one barrier ----
    BUILD_MAIN(sA, s[0][0], s[0][1], s[0][2], s[0][3],
               g[0][0], g[0][1], g[0][2], g[0][3], pA[0], pAB[0], pABC[0])
    BUILD_MAIN(sB, s[1][0], s[1][1], s[1][2], s[1][3],
               g[1][0], g[1][1], g[1][2], g[1][3], pA[1], pAB[1], pABC[1])
    BUILD_MAIN(sC, s[2][0], s[2][1], s[2][2], s[2][3],
               g[2][0], g[2][1], g[2][2], g[2][3], pA[2], pAB[2], pABC[2])
    BUILD_MAIN(sD, s[3][0], s[3][1], s[3][2], s[3][3],
               g[3][0], g[3][1], g[3][2], g[3][3], pA[3], pAB[3], pABC[3])
    asm volatile("s_waitcnt lgkmcnt(0)" ::: "memory");

    // ---- cur2: 4-stream interleaved 8-wide clusters + exact tails ----
    v2f acc0 = {0.f, 0.f}, acc1 = {0.f, 0.f};
    v2f acc2 = {0.f, 0.f}, acc3 = {0.f, 0.f};
    if (__builtin_expect(S[0] > 64 || S[1] > 64 || S[2] > 64 || S[3] > 64,
                         0)) {
      acc0 = serial_main(m1v[0][0], m1v[0][1], m1v[0][2], m1v[0][3], w2b);
      acc1 = serial_main(m1v[1][0], m1v[1][1], m1v[1][2], m1v[1][3], w2b);
      acc2 = serial_main(m1v[2][0], m1v[2][1], m1v[2][2], m1v[2][3], w2b);
      acc3 = serial_main(m1v[3][0], m1v[3][1], m1v[3][2], m1v[3][3], w2b);
    } else {
      const int na = S[0] >> 3, nb = S[1] >> 3;
      const int nc_ = S[2] >> 3, nd = S[3] >> 3;
      int ka = 0, kb = 0, kc = 0, kd = 0;
      while (ka < na && kb < nb && kc < nc_ && kd < nd) {
        { LOAD8(a_, sA, ka * 8) LOAD8(b_, sB, kb * 8)
          LOAD8(c_, sC, kc * 8) LOAD8(d_, sD, kd * 8)
          ADD8(a_, acc0) ADD8(b_, acc1) ADD8(c_, acc2) ADD8(d_, acc3) }
        ++ka; ++kb; ++kc; ++kd;
      }
      while (ka < na && kb < nb) {
        { LOAD8(e_, sA, ka * 8) LOAD8(f_, sB, kb * 8)
          ADD8(e_, acc0) ADD8(f_, acc1) }
        ++ka; ++kb;
      }
      while (kc < nc_ && kd < nd) {
        { LOAD8(i_, sC, kc * 8) LOAD8(j_, sD, kd * 8)
          ADD8(i_, acc2) ADD8(j_, acc3) }
        ++kc; ++kd;
      }
      while (ka < na) { { LOAD8(k_, sA, ka * 8) ADD8(k_, acc0) } ++ka; }
      while (kb < nb) { { LOAD8(l_, sB, kb * 8) ADD8(l_, acc1) } ++kb; }
      while (kc < nc_) { { LOAD8(m_, sC, kc * 8) ADD8(m_, acc2) } ++kc; }
      while (kd < nd) { { LOAD8(n_, sD, kd * 8) ADD8(n_, acc3) } ++kd; }
      TAILS(sA, S[0], acc0)
      TAILS(sB, S[1], acc1)
      TAILS(sC, S[2], acc2)
      TAILS(sD, S[3], acc3)
    }

    // ---- layer 2 LIF, 4 rows ----
    const float a00 = acc0.x + bb0, a01 = acc0.y + bb1;
    const float a10 = acc1.x + bb0, a11 = acc1.y + bb1;
    const float a20 = acc2.x + bb0, a21 = acc2.y + bb1;
    const float a30 = acc3.x + bb0, a31 = acc3.y + bb1;
    m2a[0] = fmaf(0.5f, m2a[0], a00) - sp2a[0];
    m2b[0] = fmaf(0.5f, m2b[0], a01) - sp2b[0];
    m2a[1] = fmaf(0.5f, m2a[1], a10) - sp2a[1];
    m2b[1] = fmaf(0.5f, m2b[1], a11) - sp2b[1];
    m2a[2] = fmaf(0.5f, m2a[2], a20) - sp2a[2];
    m2b[2] = fmaf(0.5f, m2b[2], a21) - sp2b[2];
    m2a[3] = fmaf(0.5f, m2a[3], a30) - sp2a[3];
    m2b[3] = fmaf(0.5f, m2b[3], a31) - sp2b[3];

    unsigned long long me[4], mod[4];
    int So[4], pe[4];
#pragma unroll
    for (int q = 0; q < 4; ++q) {
      const bool sa = m2a[q] > 1.0f;
      const bool sb = m2b[q] > 1.0f;
      me[q] = __ballot(sa);
      mod[q] = __ballot(sb);
      sp2a[q] = sa ? 1.0f : 0.0f;
      sp2b[q] = sb ? 1.0f : 0.0f;
      pe[q] = (int)__popcll(me[q]);
      So[q] = pe[q] + (int)__popcll(mod[q]);
    }

    // ---- output-layer lists (evens ascending, then odds), one barrier ----
#pragma unroll
    for (int q = 0; q < 4; ++q) {
      int* sq = scr + q * 64;
      if (sp2a[q] != 0.f) sq[mbcnt64(me[q])] = or0;
      if (sp2b[q] != 0.f) {
        const int rk = pe[q] + mbcnt64(mod[q]);
        if (rk < 64) sq[rk] = or1;
      }
    }
    asm volatile("s_waitcnt lgkmcnt(0)" ::: "memory");

    float co0 = 0.f, co1 = 0.f, co2 = 0.f, co3 = 0.f;
    if (__builtin_expect(So[0] > 64 || So[1] > 64 || So[2] > 64 ||
                             So[3] > 64,
                         0)) {
      co0 = serial_out(m2a[0], m2b[0], wob);
      co1 = serial_out(m2a[1], m2b[1], wob);
      co2 = serial_out(m2a[2], m2b[2], wob);
      co3 = serial_out(m2a[3], m2b[3], wob);
    } else {
      const int na = So[0] >> 3, nb = So[1] >> 3;
      const int nc_ = So[2] >> 3, nd = So[3] >> 3;
      int ka = 0, kb = 0, kc = 0, kd = 0;
      while (ka < na && kb < nb && kc < nc_ && kd < nd) {
        { OLOAD8(a_, sA, ka * 8) OLOAD8(b_, sB, kb * 8)
          OLOAD8(c_, sC, kc * 8) OLOAD8(d_, sD, kd * 8)
          OADD8(a_, co0) OADD8(b_, co1) OADD8(c_, co2) OADD8(d_, co3) }
        ++ka; ++kb; ++kc; ++kd;
      }
      while (ka < na && kb < nb) {
        { OLOAD8(e_, sA, ka * 8) OLOAD8(f_, sB, kb * 8)
          OADD8(e_, co0) OADD8(f_, co1) }
        ++ka; ++kb;
      }
      while (kc < nc_ && kd < nd) {
        { OLOAD8(i_, sC, kc * 8) OLOAD8(j_, sD, kd * 8)
          OADD8(i_, co2) OADD8(j_, co3) }
        ++kc; ++kd;
      }
      while (ka < na) { { OLOAD8(k_, sA, ka * 8) OADD8(k_, co0) } ++ka; }
      while (kb < nb) { { OLOAD8(l_, sB, kb * 8) OADD8(l_, co1) } ++kb; }
      while (kc < nc_) { { OLOAD8(m_, sC, kc * 8) OADD8(m_, co2) } ++kc; }
      while (kd < nd) { { OLOAD8(n_, sD, kd * 8) OADD8(n_, co3) } ++kd; }
      OTAILS(sA, So[0], co0)
      OTAILS(sB, So[1], co1)
      OTAILS(sC, So[2], co2)
      OTAILS(sD, So[3], co3)
    }
    co0 += bol;
    co1 += bol;
    co2 += bol;
    co3 += bol;

    // ---- output LIF + spike count, 4 rows ----
    mo[0] = fmaf(0.5f, mo[0], co0) - spo[0];
    mo[1] = fmaf(0.5f, mo[1], co1) - spo[1];
    mo[2] = fmaf(0.5f, mo[2], co2) - spo[2];
    mo[3] = fmaf(0.5f, mo[3], co3) - spo[3];
#pragma unroll
    for (int q = 0; q < 4; ++q) {
      const bool so = mo[q] > 1.0f;
      spo[q] = so ? 1.0f : 0.0f;
      cnt[q] += spo[q];
    }
  }

  if (l < NC) {
#pragma unroll
    for (int q = 0; q < 4; ++q) out[(b0 + q) * NC + l] = cnt[q];
  }
#undef LOAD8
#undef ADD8
#undef TAILS
#undef OLOAD8
#undef OADD8
#undef OTAILS
#undef BUILD_MAIN
}

// ---------------------------------------------------------------------------
extern "C" void kernel_launch(void* const* d_in, const int* in_sizes, int n_in,
                              void* d_out, int out_size, void* d_ws,
                              size_t ws_size, hipStream_t stream) {
  const float* x  = (const float*)d_in[0];
  const float* W1 = (const float*)d_in[1];
  const float* b1 = (const float*)d_in[2];
  const float* W2 = (const float*)d_in[3];
  const float* b2 = (const float*)d_in[4];
  const float* Wo = (const float*)d_in[5];
  const float* bo = (const float*)d_in[6];
  const int* nsp  = (const int*)d_in[7];
  float* outp = (float*)d_out;

  // ws layout: cur1 (16384*256 f) | W2T (32768 f) | WoT (1280 f)
  float* cur1 = (float*)d_ws;
  float* W2Tg = cur1 + (size_t)B_TOT * H1;
  float* WoTg = W2Tg + H1 * H2;

  gemm1_fused_kernel<<<257, 256, 0, stream>>>(x, W1, b1, W2, Wo, cur1, W2Tg,
                                              WoTg);

  hipFuncSetAttribute((const void*)snn_kernel,
                      hipFuncAttributeMaxDynamicSharedMemorySize, LDS_BYTES);
  snn_kernel<<<256, 1024, LDS_BYTES, stream>>>(cur1, W2Tg, WoTg, b2, bo, nsp,
                                               outp);
}